// Round 13
// baseline (92.996 us; speedup 1.0000x reference)
//
#include <hip/hip_runtime.h>

// MaskedDenseLayer round 13: pure streaming-VALU formulation.
// out[b,o] = relu(sum_i x[b,i]*kernel[i,o]*masks[state[b],i,o] + b0[o])
//
// Insight: arithmetic intensity is ~1 FLOP/byte (masks used ONCE). VALU
// f32 floor = 5.2us, mask stream = 51.4MB (L3-resident across replays).
// So: the lane that loads mask[i][o] consumes it. No MFMA, no fragments,
// no staging ring, no barriers in the i-loop. x broadcasts from LDS via
// wave-uniform ds_read_b128 (broadcast = conflict-free).
//
// Grid 256 = (s = bid>>4) x (ot = bid&15, 64 cols). 1024 thr = 16 waves,
// wave w owns i in [w*49, w*49+49). Per block: stage <=48 gathered x rows
// (f32, 150KB dynamic LDS, 1 block/CU); per 4-i: 8 coalesced dword loads
// (mask+kern, 256B/instr) + 4 muls -> w0..w3; per live sample j: 1
// ds_read_b128 (x[j][i..i+3], uniform addr) + 4 fmaf into acc[j].
// j<nj is a wave-uniform branch (skips dead slots; avg ns=32 of JC=48).
// Epilogue: 16-wave reduce via LDS aliased over xs (4 slices of 12),
// fused bias+relu store. Chunk loop handles any ns (incl >48). All-f32.

#define IN_DIM 784
#define OUT_DIM 1024
#define BS 512
#define JC 48            // sample slots per chunk (acc registers)

__global__ __launch_bounds__(1024, 4) void made_stream(
    const float* __restrict__ x,      // [512, 784]
    const int*   __restrict__ state,  // [512]
    const float* __restrict__ masks,  // [16, 784, 1024]
    const float* __restrict__ kern,   // [784, 1024]
    const float* __restrict__ bias,   // [1024]
    float*       __restrict__ out)    // [512, 1024]
{
    extern __shared__ float xs[];     // [JC][IN_DIM] f32 = 150528 B; aliased
                                      // by red[16][12][64] in the epilogue
    __shared__ int list[BS];
    __shared__ int cnt;

    const int tid  = threadIdx.x;
    const int lane = tid & 63;
    const int w    = tid >> 6;        // 16 waves = 16 i-chunks
    const int s    = blockIdx.x >> 4;
    const int ot   = blockIdx.x & 15;
    const int o    = ot * 64 + lane;

    if (tid == 0) cnt = 0;
    __syncthreads();
    if (tid < BS) {
        int st = state[tid];
        if (st == s) { int p = atomicAdd(&cnt, 1); list[p] = tid; }
    }
    __syncthreads();
    const int ns = cnt;
    if (ns == 0) return;              // block-uniform

    const float* mS = masks + (size_t)s * IN_DIM * OUT_DIM + o;
    const float* kS = kern + o;
    const int i0 = w * 49;

    for (int base = 0; base < ns; base += JC) {
        const int nj = (ns - base < JC) ? (ns - base) : JC;

        // ---- stage x rows [base, base+nj) into LDS (coalesced float4) ----
        for (int idx = tid; idx < JC * (IN_DIM / 4); idx += 1024) {
            int r = idx / (IN_DIM / 4), c = idx % (IN_DIM / 4);
            if (r < nj) {
                float4 v = ((const float4*)(x + (size_t)list[base + r] * IN_DIM))[c];
                ((float4*)(xs + r * IN_DIM))[c] = v;
            }
        }
        __syncthreads();

        float acc[JC];
#pragma unroll
        for (int j = 0; j < JC; ++j) acc[j] = 0.f;

        // ---- 12 groups of 4 i, then 1 tail i (49 per wave) ----
#pragma unroll
        for (int g = 0; g < 12; ++g) {
            const int i = i0 + g * 4;
            float w0 = kS[(size_t)(i    ) * OUT_DIM] * mS[(size_t)(i    ) * OUT_DIM];
            float w1 = kS[(size_t)(i + 1) * OUT_DIM] * mS[(size_t)(i + 1) * OUT_DIM];
            float w2 = kS[(size_t)(i + 2) * OUT_DIM] * mS[(size_t)(i + 2) * OUT_DIM];
            float w3 = kS[(size_t)(i + 3) * OUT_DIM] * mS[(size_t)(i + 3) * OUT_DIM];
#pragma unroll
            for (int j = 0; j < JC; ++j) {
                if (j < nj) {                     // wave-uniform skip
                    float4 xv = *(const float4*)(xs + j * IN_DIM + i);
                    acc[j] = fmaf(xv.x, w0, acc[j]);
                    acc[j] = fmaf(xv.y, w1, acc[j]);
                    acc[j] = fmaf(xv.z, w2, acc[j]);
                    acc[j] = fmaf(xv.w, w3, acc[j]);
                }
            }
        }
        {
            const int i = i0 + 48;
            float wt = kS[(size_t)i * OUT_DIM] * mS[(size_t)i * OUT_DIM];
#pragma unroll
            for (int j = 0; j < JC; ++j)
                if (j < nj) acc[j] = fmaf(xs[j * IN_DIM + i], wt, acc[j]);
        }

        // ---- reduce 16 waves via LDS aliased over xs: 4 slices of 12 ----
        float (*red)[12][64] = (float (*)[12][64])xs;
#pragma unroll 1
        for (int sl = 0; sl < 4; ++sl) {
            __syncthreads();          // region free (stagers/readers done)
#pragma unroll
            for (int r = 0; r < 12; ++r) red[w][r][lane] = acc[sl * 12 + r];
            __syncthreads();
            if (tid < 768) {
                int r = tid >> 6, ol = tid & 63;
                float v = 0.f;
#pragma unroll
                for (int q = 0; q < 16; ++q) v += red[q][r][ol];
                int sr = base + sl * 12 + r;
                if (sr < ns) {
                    float ov = v + bias[ot * 64 + ol];
                    out[(size_t)list[sr] * OUT_DIM + ot * 64 + ol] = ov > 0.f ? ov : 0.f;
                }
            }
        }
        __syncthreads();              // before next chunk re-stages xs
    }
}

extern "C" void kernel_launch(void* const* d_in, const int* in_sizes, int n_in,
                              void* d_out, int out_size, void* d_ws, size_t ws_size,
                              hipStream_t stream) {
    (void)in_sizes; (void)n_in; (void)out_size; (void)d_ws; (void)ws_size;
    const float* x     = (const float*)d_in[0];
    const int*   state = (const int*)  d_in[1];
    const float* masks = (const float*)d_in[2];
    const float* kern  = (const float*)d_in[3];
    const float* b0    = (const float*)d_in[4];
    float* out = (float*)d_out;

    const size_t dynLds = (size_t)JC * IN_DIM * sizeof(float);   // 150528 B
    static bool attrSet = false;
    if (!attrSet) {   // host-side attr, idempotent, not a stream op
        hipFuncSetAttribute((const void*)made_stream,
                            hipFuncAttributeMaxDynamicSharedMemorySize,
                            (int)dynLds);
        attrSet = true;
    }
    made_stream<<<dim3(256), dim3(1024), dynLds, stream>>>(
        x, state, masks, kern, b0, out);
}

// Round 14
// 52.114 us; speedup vs baseline: 1.7845x; 1.7845x over previous
//
#include <hip/hip_runtime.h>

// MaskedDenseLayer round 14: round-13 streaming-VALU kernel with the rule-#20
// spill fixed (epilogue slice loop is now fully unrolled -> acc[] indices are
// all compile-time -> accumulators stay in VGPRs; round 13 had runtime sl ->
// whole acc[48] in scratch: VGPR=64, WRITE_SIZE=417MB, 97us).
//
// out[b,o] = relu(sum_i x[b,i]*kernel[i,o]*masks[state[b],i,o] + b0[o])
//
// Structure (unchanged): arithmetic intensity ~1 FLOP/byte (masks used once)
// -> the lane that loads mask[i][o] consumes it. No MFMA, no staging ring,
// no barriers in the i-loop. Grid 256 = (s, ot of 64 cols), 1024 thr = 16
// waves, wave w owns i in [w*49, w*49+49). x rows (<=48) staged f32 in 150KB
// dynamic LDS; per 4-i: 8 coalesced 256B loads (mask+kern) + 4 muls; per
// live sample j: 1 uniform-address ds_read_b128 (broadcast, conflict-free)
// + 4 fmaf into acc[j]. j<nj skip is wave-uniform (scalar branch). Epilogue:
// 16-wave reduce via LDS aliased over xs, 4 fully-unrolled slices of 12,
// fused bias+relu store. All-f32 (absmax ~1e-5 class).

#define IN_DIM 784
#define OUT_DIM 1024
#define BS 512
#define JC 48            // sample slots per chunk (fits ns w.p. ~99.8%)

__global__ __launch_bounds__(1024, 4) void made_stream2(
    const float* __restrict__ x,      // [512, 784]
    const int*   __restrict__ state,  // [512]
    const float* __restrict__ masks,  // [16, 784, 1024]
    const float* __restrict__ kern,   // [784, 1024]
    const float* __restrict__ bias,   // [1024]
    float*       __restrict__ out)    // [512, 1024]
{
    extern __shared__ float xs[];     // [JC][IN_DIM] f32 = 150528 B; epilogue
                                      // aliases first 48KB as red[16][12][64]
    __shared__ int list[BS];
    __shared__ int cnt;

    const int tid  = threadIdx.x;
    const int lane = tid & 63;
    const int w    = tid >> 6;        // 16 waves = 16 i-chunks
    const int s    = blockIdx.x >> 4;
    const int ot   = blockIdx.x & 15;
    const int o    = ot * 64 + lane;

    if (tid == 0) cnt = 0;
    __syncthreads();
    if (tid < BS) {
        int st = state[tid];
        if (st == s) { int p = atomicAdd(&cnt, 1); list[p] = tid; }
    }
    __syncthreads();
    const int ns = cnt;
    if (ns == 0) return;              // block-uniform

    const float* mS = masks + (size_t)s * IN_DIM * OUT_DIM + o;
    const float* kS = kern + o;
    const int i0 = w * 49;

    for (int base = 0; base < ns; base += JC) {
        const int nj = (ns - base < JC) ? (ns - base) : JC;

        // ---- stage x rows [base, base+nj) into LDS (coalesced float4) ----
        for (int idx = tid; idx < JC * (IN_DIM / 4); idx += 1024) {
            int r = idx / (IN_DIM / 4), c = idx % (IN_DIM / 4);
            if (r < nj) {
                float4 v = ((const float4*)(x + (size_t)list[base + r] * IN_DIM))[c];
                ((float4*)(xs + r * IN_DIM))[c] = v;
            }
        }
        __syncthreads();

        float acc[JC];
#pragma unroll
        for (int j = 0; j < JC; ++j) acc[j] = 0.f;

        // ---- 12 groups of 4 i, then 1 tail i (49 per wave) ----
#pragma unroll
        for (int g = 0; g < 12; ++g) {
            const int i = i0 + g * 4;
            float w0 = kS[(size_t)(i    ) * OUT_DIM] * mS[(size_t)(i    ) * OUT_DIM];
            float w1 = kS[(size_t)(i + 1) * OUT_DIM] * mS[(size_t)(i + 1) * OUT_DIM];
            float w2 = kS[(size_t)(i + 2) * OUT_DIM] * mS[(size_t)(i + 2) * OUT_DIM];
            float w3 = kS[(size_t)(i + 3) * OUT_DIM] * mS[(size_t)(i + 3) * OUT_DIM];
#pragma unroll
            for (int j = 0; j < JC; ++j) {
                if (j < nj) {                     // wave-uniform scalar skip
                    float4 xv = *(const float4*)(xs + j * IN_DIM + i);
                    acc[j] = fmaf(xv.x, w0, acc[j]);
                    acc[j] = fmaf(xv.y, w1, acc[j]);
                    acc[j] = fmaf(xv.z, w2, acc[j]);
                    acc[j] = fmaf(xv.w, w3, acc[j]);
                }
            }
        }
        {
            const int i = i0 + 48;
            float wt = kS[(size_t)i * OUT_DIM] * mS[(size_t)i * OUT_DIM];
#pragma unroll
            for (int j = 0; j < JC; ++j)
                if (j < nj) acc[j] = fmaf(xs[j * IN_DIM + i], wt, acc[j]);
        }

        // ---- reduce 16 waves via LDS alias: 4 slices of 12, FULLY unrolled
        //      (sl compile-time -> acc[] indices static, rule #20) ----
        float (*red)[12][64] = (float (*)[12][64])xs;
#pragma unroll
        for (int sl = 0; sl < 4; ++sl) {
            __syncthreads();          // region free (compute / prev slice done)
#pragma unroll
            for (int r = 0; r < 12; ++r) red[w][r][lane] = acc[sl * 12 + r];
            __syncthreads();
            if (tid < 768) {
                int r = tid >> 6, ol = tid & 63;
                float v = 0.f;
#pragma unroll
                for (int q = 0; q < 16; ++q) v += red[q][r][ol];
                int sr = base + sl * 12 + r;
                if (sr < ns) {
                    float ov = v + bias[ot * 64 + ol];
                    out[(size_t)list[sr] * OUT_DIM + ot * 64 + ol] = ov > 0.f ? ov : 0.f;
                }
            }
        }
        __syncthreads();              // before next chunk re-stages xs
    }
}

extern "C" void kernel_launch(void* const* d_in, const int* in_sizes, int n_in,
                              void* d_out, int out_size, void* d_ws, size_t ws_size,
                              hipStream_t stream) {
    (void)in_sizes; (void)n_in; (void)out_size; (void)d_ws; (void)ws_size;
    const float* x     = (const float*)d_in[0];
    const int*   state = (const int*)  d_in[1];
    const float* masks = (const float*)d_in[2];
    const float* kern  = (const float*)d_in[3];
    const float* b0    = (const float*)d_in[4];
    float* out = (float*)d_out;

    const size_t dynLds = (size_t)JC * IN_DIM * sizeof(float);   // 150528 B
    hipFuncSetAttribute((const void*)made_stream2,
                        hipFuncAttributeMaxDynamicSharedMemorySize,
                        (int)dynLds);
    made_stream2<<<dim3(256), dim3(1024), dynLds, stream>>>(
        x, state, masks, kern, b0, out);
}